// Round 1
// baseline (6154.811 us; speedup 1.0000x reference)
//
#include <hip/hip_runtime.h>

#define BN_EPS 1e-5f

__device__ __forceinline__ void atomicAdd4(float* p, float4 v) {
    unsafeAtomicAdd(p + 0, v.x);
    unsafeAtomicAdd(p + 1, v.y);
    unsafeAtomicAdd(p + 2, v.z);
    unsafeAtomicAdd(p + 3, v.w);
}

// -------- scatter: AGG[dst] += H[src]  (edge-parallel, 16 threads/edge) -----
__global__ __launch_bounds__(256) void k_scatter(const float4* __restrict__ H,
        const int* __restrict__ src, const int* __restrict__ dst,
        float* __restrict__ AGG, int nedges)
{
    int u = blockIdx.x * 256 + threadIdx.x;
    int total = nedges * 16;
    if (u >= total) return;
    int e = u >> 4, q = u & 15;
    int s = src[e], d = dst[e];
    float4 v = H[(size_t)s * 16 + q];
    atomicAdd4(AGG + (size_t)d * 64 + q * 4, v);
}

// -------- GEMM with GIN combine fused into the input read -------------------
// V[r][c] = sum_k ((1+eps)*H[r][k] + AGG[r][k]) * W[k][c] + bias[c]
__global__ __launch_bounds__(256) void k_gemm_in(const float4* __restrict__ H,
        const float4* __restrict__ AGG, const float* __restrict__ W,
        const float* __restrict__ bias, const float* __restrict__ epsp, int layer,
        float4* __restrict__ V, int M)
{
    __shared__ float4 Bs[64][16];   // W tile, 16 KB
    int tid = threadIdx.x;
    const float4* W4 = (const float4*)W;
#pragma unroll
    for (int i = 0; i < 4; ++i)
        ((float4*)Bs)[tid + 256 * i] = W4[tid + 256 * i];
    float epsv = 1.0f + epsp[layer];
    __syncthreads();

    int row = blockIdx.x * 256 + tid;
    if (row >= M) return;
    const float4* hr = H + (size_t)row * 16;
    const float4* ar = AGG + (size_t)row * 16;

    float4 acc[16];
    const float4* b4 = (const float4*)bias;
#pragma unroll
    for (int c = 0; c < 16; ++c) acc[c] = b4[c];

#pragma unroll
    for (int kc = 0; kc < 4; ++kc) {
        float uv[16];
#pragma unroll
        for (int j = 0; j < 4; ++j) {
            float4 hv = hr[kc * 4 + j];
            float4 av = ar[kc * 4 + j];
            uv[j * 4 + 0] = epsv * hv.x + av.x;
            uv[j * 4 + 1] = epsv * hv.y + av.y;
            uv[j * 4 + 2] = epsv * hv.z + av.z;
            uv[j * 4 + 3] = epsv * hv.w + av.w;
        }
#pragma unroll
        for (int k = 0; k < 16; ++k) {
            float a = uv[k];
            int kk = kc * 16 + k;
#pragma unroll
            for (int c = 0; c < 16; ++c) {
                float4 bv = Bs[kk][c];
                acc[c].x += a * bv.x;
                acc[c].y += a * bv.y;
                acc[c].z += a * bv.z;
                acc[c].w += a * bv.w;
            }
        }
    }
    float4* vr = V + (size_t)row * 16;
#pragma unroll
    for (int c = 0; c < 16; ++c) vr[c] = acc[c];
}

// -------- GEMM with input BN+ReLU fused (BN params from raw stats) ---------
// Z[r][c] = sum_k relu(a[k]*Vin[r][k]+b[k]) * W[k][c] + bias[c]
__global__ __launch_bounds__(256) void k_gemm_bn(const float4* __restrict__ Vin,
        const float* __restrict__ S, const float* __restrict__ g,
        const float* __restrict__ bt, const float* __restrict__ W,
        const float* __restrict__ bias, float4* __restrict__ Z, int M)
{
    __shared__ float4 Bs[64][16];
    __shared__ float As_[64];
    __shared__ float Bb_[64];
    int tid = threadIdx.x;
    const float4* W4 = (const float4*)W;
#pragma unroll
    for (int i = 0; i < 4; ++i)
        ((float4*)Bs)[tid + 256 * i] = W4[tid + 256 * i];
    if (tid < 64) {
        float invM = 1.0f / (float)M;
        float mu = S[tid] * invM;
        float var = S[64 + tid] * invM - mu * mu;
        float a = g[tid] * rsqrtf(var + BN_EPS);
        As_[tid] = a;
        Bb_[tid] = bt[tid] - a * mu;
    }
    __syncthreads();

    int row = blockIdx.x * 256 + tid;
    if (row >= M) return;
    const float4* vr = Vin + (size_t)row * 16;

    float4 acc[16];
    const float4* b4 = (const float4*)bias;
#pragma unroll
    for (int c = 0; c < 16; ++c) acc[c] = b4[c];

#pragma unroll
    for (int kc = 0; kc < 4; ++kc) {
        float uv[16];
#pragma unroll
        for (int j = 0; j < 4; ++j) {
            float4 hv = vr[kc * 4 + j];
            int kb = kc * 16 + j * 4;
            uv[j * 4 + 0] = fmaxf(As_[kb + 0] * hv.x + Bb_[kb + 0], 0.0f);
            uv[j * 4 + 1] = fmaxf(As_[kb + 1] * hv.y + Bb_[kb + 1], 0.0f);
            uv[j * 4 + 2] = fmaxf(As_[kb + 2] * hv.z + Bb_[kb + 2], 0.0f);
            uv[j * 4 + 3] = fmaxf(As_[kb + 3] * hv.w + Bb_[kb + 3], 0.0f);
        }
#pragma unroll
        for (int k = 0; k < 16; ++k) {
            float a = uv[k];
            int kk = kc * 16 + k;
#pragma unroll
            for (int c = 0; c < 16; ++c) {
                float4 bv = Bs[kk][c];
                acc[c].x += a * bv.x;
                acc[c].y += a * bv.y;
                acc[c].z += a * bv.z;
                acc[c].w += a * bv.w;
            }
        }
    }
    float4* zr = Z + (size_t)row * 16;
#pragma unroll
    for (int c = 0; c < 16; ++c) zr[c] = acc[c];
}

// -------- column stats: S[0..63]=sum, S[64..127]=sumsq ----------------------
__global__ __launch_bounds__(256) void k_stats(const float4* __restrict__ V,
        float* __restrict__ S, int M)
{
    int tid = threadIdx.x;
    int q = tid & 15, rs = tid >> 4;
    float4 sum = make_float4(0.f, 0.f, 0.f, 0.f);
    float4 ss = make_float4(0.f, 0.f, 0.f, 0.f);
    for (int r = blockIdx.x * 16 + rs; r < M; r += gridDim.x * 16) {
        float4 v = V[(size_t)r * 16 + q];
        sum.x += v.x; sum.y += v.y; sum.z += v.z; sum.w += v.w;
        ss.x += v.x * v.x; ss.y += v.y * v.y; ss.z += v.z * v.z; ss.w += v.w * v.w;
    }
    // reduce across the 4 row-slots within each wave (lanes ^16, ^32)
    sum.x += __shfl_xor(sum.x, 16); sum.y += __shfl_xor(sum.y, 16);
    sum.z += __shfl_xor(sum.z, 16); sum.w += __shfl_xor(sum.w, 16);
    ss.x += __shfl_xor(ss.x, 16);   ss.y += __shfl_xor(ss.y, 16);
    ss.z += __shfl_xor(ss.z, 16);   ss.w += __shfl_xor(ss.w, 16);
    sum.x += __shfl_xor(sum.x, 32); sum.y += __shfl_xor(sum.y, 32);
    sum.z += __shfl_xor(sum.z, 32); sum.w += __shfl_xor(sum.w, 32);
    ss.x += __shfl_xor(ss.x, 32);   ss.y += __shfl_xor(ss.y, 32);
    ss.z += __shfl_xor(ss.z, 32);   ss.w += __shfl_xor(ss.w, 32);

    __shared__ float4 LS[4][16];
    __shared__ float4 LQ[4][16];
    int wave = tid >> 6, lane = tid & 63;
    if (lane < 16) { LS[wave][lane] = sum; LQ[wave][lane] = ss; }
    __syncthreads();
    if (tid < 16) {
        float4 s0 = LS[0][tid], q0 = LQ[0][tid];
#pragma unroll
        for (int w = 1; w < 4; ++w) {
            float4 sw = LS[w][tid], qw = LQ[w][tid];
            s0.x += sw.x; s0.y += sw.y; s0.z += sw.z; s0.w += sw.w;
            q0.x += qw.x; q0.y += qw.y; q0.z += qw.z; q0.w += qw.w;
        }
        atomicAdd4(S + tid * 4, s0);
        atomicAdd4(S + 64 + tid * 4, q0);
    }
}

// -------- finalize: H = relu(a*Z+b), and zero AGG for next layer ------------
__global__ __launch_bounds__(256) void k_finalize(const float4* __restrict__ Z,
        const float* __restrict__ S, const float* __restrict__ g,
        const float* __restrict__ bt, float4* __restrict__ H,
        float4* __restrict__ AGG, int M, float invM)
{
    int q = threadIdx.x & 15;
    float a4[4], b4[4];
#pragma unroll
    for (int j = 0; j < 4; ++j) {
        int c = q * 4 + j;
        float mu = S[c] * invM;
        float var = S[64 + c] * invM - mu * mu;
        float a = g[c] * rsqrtf(var + BN_EPS);
        a4[j] = a;
        b4[j] = bt[c] - a * mu;
    }
    int total = M * 16;
    float4 zero = make_float4(0.f, 0.f, 0.f, 0.f);
    for (int u = blockIdx.x * 256 + threadIdx.x; u < total; u += gridDim.x * 256) {
        float4 z = Z[u];
        float4 h;
        h.x = fmaxf(a4[0] * z.x + b4[0], 0.f);
        h.y = fmaxf(a4[1] * z.y + b4[1], 0.f);
        h.z = fmaxf(a4[2] * z.z + b4[2], 0.f);
        h.w = fmaxf(a4[3] * z.w + b4[3], 0.f);
        H[u] = h;
        AGG[u] = zero;
    }
}

// -------- per-graph mean pool (run-length local accumulation) ---------------
__global__ __launch_bounds__(256) void k_pool(const float4* __restrict__ H,
        const int* __restrict__ batch, float* __restrict__ POOL,
        float* __restrict__ CNT, int M, int chunk)
{
    int start = blockIdx.x * chunk;
    int end = min(M, start + chunk);
    int q = threadIdx.x & 15, rs = threadIdx.x >> 4;
    int curg = -1;
    float4 acc = make_float4(0.f, 0.f, 0.f, 0.f);
    float cl = 0.f;
    for (int r = start + rs; r < end; r += 16) {
        int gg = batch[r];
        float4 v = H[(size_t)r * 16 + q];
        if (gg != curg) {
            if (curg >= 0) {
                atomicAdd4(POOL + (size_t)curg * 64 + q * 4, acc);
                if (q == 0) unsafeAtomicAdd(CNT + curg, cl);
            }
            curg = gg;
            acc = make_float4(0.f, 0.f, 0.f, 0.f);
            cl = 0.f;
        }
        acc.x += v.x; acc.y += v.y; acc.z += v.z; acc.w += v.w;
        cl += 1.f;
    }
    if (curg >= 0) {
        atomicAdd4(POOL + (size_t)curg * 64 + q * 4, acc);
        if (q == 0) unsafeAtomicAdd(CNT + curg, cl);
    }
}

// -------- head: out[g] = dot(POOL[g]/cnt, Wh) + bh --------------------------
__global__ __launch_bounds__(256) void k_head(const float* __restrict__ POOL,
        const float* __restrict__ CNT, const float* __restrict__ Wh,
        const float* __restrict__ bh, float* __restrict__ OUT, int ngraph)
{
    int lane = threadIdx.x & 63;
    int wv = threadIdx.x >> 6;
    int gidx = blockIdx.x * 4 + wv;
    if (gidx >= ngraph) return;
    float c = fmaxf(CNT[gidx], 1.0f);
    float v = POOL[(size_t)gidx * 64 + lane] / c * Wh[lane];
#pragma unroll
    for (int off = 1; off < 64; off <<= 1) v += __shfl_xor(v, off);
    if (lane == 0) OUT[gidx] = v + bh[0];
}

extern "C" void kernel_launch(void* const* d_in, const int* in_sizes, int n_in,
                              void* d_out, int out_size, void* d_ws, size_t ws_size,
                              hipStream_t stream)
{
    const float* x   = (const float*)d_in[0];
    const int*   ei  = (const int*)d_in[1];
    const int*   bat = (const int*)d_in[2];
    const float* W1  = (const float*)d_in[3];
    const float* b1  = (const float*)d_in[4];
    const float* g1  = (const float*)d_in[5];
    const float* bt1 = (const float*)d_in[6];
    const float* W2  = (const float*)d_in[7];
    const float* b2  = (const float*)d_in[8];
    const float* g2  = (const float*)d_in[9];
    const float* bt2 = (const float*)d_in[10];
    const float* eps = (const float*)d_in[11];
    const float* Wh  = (const float*)d_in[12];
    const float* bh  = (const float*)d_in[13];
    float* out = (float*)d_out;

    int M = in_sizes[0] / 64;
    int nedges = in_sizes[1] / 2;
    const int* src = ei;
    const int* dst = ei + nedges;
    const int NG = 512;

    float* ws = (float*)d_ws;
    size_t NE = (size_t)M * 64;
    float* h    = ws;
    float* agg  = ws + NE;
    float* v    = ws + 2 * NE;
    float* z    = ws + 3 * NE;
    float* S1   = ws + 4 * NE;          // 4 layers x 128
    float* S2   = S1 + 512;             // 4 layers x 128
    float* POOL = S2 + 512;             // 512 x 64
    float* CNT  = POOL + (size_t)NG * 64;  // 512

    hipMemsetAsync(agg, 0, NE * sizeof(float), stream);
    hipMemsetAsync(S1, 0, (512 + 512 + (size_t)NG * 64 + NG) * sizeof(float), stream);

    int gemmGrid = (M + 255) / 256;
    int scatGrid = (nedges * 16 + 255) / 256;

    for (int i = 0; i < 4; ++i) {
        const float* hin = (i == 0) ? x : h;
        k_scatter<<<scatGrid, 256, 0, stream>>>((const float4*)hin, src, dst, agg, nedges);
        k_gemm_in<<<gemmGrid, 256, 0, stream>>>((const float4*)hin, (const float4*)agg,
                W1 + (size_t)i * 4096, b1 + i * 64, eps, i, (float4*)v, M);
        k_stats<<<400, 256, 0, stream>>>((const float4*)v, S1 + i * 128, M);
        k_gemm_bn<<<gemmGrid, 256, 0, stream>>>((const float4*)v, S1 + i * 128,
                g1 + i * 64, bt1 + i * 64, W2 + (size_t)i * 4096, b2 + i * 64,
                (float4*)z, M);
        k_stats<<<400, 256, 0, stream>>>((const float4*)z, S2 + i * 128, M);
        k_finalize<<<2048, 256, 0, stream>>>((const float4*)z, S2 + i * 128,
                g2 + i * 64, bt2 + i * 64, (float4*)h, (float4*)agg, M, 1.0f / M);
    }
    int chunk = (M + 511) / 512;
    k_pool<<<512, 256, 0, stream>>>((const float4*)h, bat, POOL, CNT, M, chunk);
    k_head<<<(NG + 3) / 4, 256, 0, stream>>>(POOL, CNT, Wh, bh, out, NG);
}

// Round 2
// 1098.474 us; speedup vs baseline: 5.6031x; 5.6031x over previous
//
#include <hip/hip_runtime.h>

#define BN_EPS 1e-5f

__device__ __forceinline__ void atomicAdd4(float* p, float4 v) {
    unsafeAtomicAdd(p + 0, v.x);
    unsafeAtomicAdd(p + 1, v.y);
    unsafeAtomicAdd(p + 2, v.z);
    unsafeAtomicAdd(p + 3, v.w);
}

// ===================== CSR build (once, reused for all 4 layers) ============

__global__ __launch_bounds__(256) void k_count(const int* __restrict__ dst,
        int* __restrict__ deg, int nedges)
{
    int e = blockIdx.x * 256 + threadIdx.x;
    if (e < nedges) atomicAdd(&deg[dst[e]], 1);
}

// per-256-chunk inclusive scan
__global__ __launch_bounds__(256) void k_scanA(const int* __restrict__ deg,
        int* __restrict__ incl, int* __restrict__ bsum, int N)
{
    __shared__ int tmp[256];
    int i = blockIdx.x * 256 + threadIdx.x;
    int d = (i < N) ? deg[i] : 0;
    tmp[threadIdx.x] = d;
    __syncthreads();
    for (int off = 1; off < 256; off <<= 1) {
        int val = (threadIdx.x >= off) ? tmp[threadIdx.x - off] : 0;
        __syncthreads();
        tmp[threadIdx.x] += val;
        __syncthreads();
    }
    if (i < N) incl[i] = tmp[threadIdx.x];
    if (threadIdx.x == 255) bsum[blockIdx.x] = tmp[255];
}

// single-block scan of block sums -> exclusive block bases (NB <= 512)
__global__ __launch_bounds__(512) void k_scanB(int* __restrict__ bsum, int NB)
{
    __shared__ int tmp[512];
    int tid = threadIdx.x;
    int d = (tid < NB) ? bsum[tid] : 0;
    tmp[tid] = d;
    __syncthreads();
    for (int off = 1; off < 512; off <<= 1) {
        int val = (tid >= off) ? tmp[tid - off] : 0;
        __syncthreads();
        tmp[tid] += val;
        __syncthreads();
    }
    if (tid < NB) bsum[tid] = tmp[tid] - d;   // exclusive
}

__global__ __launch_bounds__(256) void k_scanC(const int* __restrict__ deg,
        const int* __restrict__ incl, const int* __restrict__ bsum,
        int* __restrict__ rowptr, int* __restrict__ fill, int N)
{
    int i = blockIdx.x * 256 + threadIdx.x;
    if (i >= N) return;
    int d = deg[i];
    int excl = incl[i] - d + bsum[blockIdx.x];
    rowptr[i] = excl;
    fill[i] = excl;
    if (i == N - 1) rowptr[N] = excl + d;
}

__global__ __launch_bounds__(256) void k_fill(const int* __restrict__ src,
        const int* __restrict__ dst, int* __restrict__ fill,
        int* __restrict__ csr, int nedges)
{
    int e = blockIdx.x * 256 + threadIdx.x;
    if (e >= nedges) return;
    int pos = atomicAdd(&fill[dst[e]], 1);
    csr[pos] = src[e];
}

// ===================== gather aggregation + GIN combine =====================
// U[d][lane] = (1+eps)*H[d][lane] + sum_{s in adj(d)} H[s][lane]
__global__ __launch_bounds__(256) void k_gather(const float* __restrict__ H,
        const int* __restrict__ rowptr, const int* __restrict__ csr,
        const float* __restrict__ epsp, int layer,
        float* __restrict__ U, int N)
{
    int wave = threadIdx.x >> 6;
    int lane = threadIdx.x & 63;
    int node = blockIdx.x * 4 + wave;
    if (node >= N) return;
    int start = rowptr[node], end = rowptr[node + 1];
    float acc = 0.f;
    for (int base = start; base < end; base += 64) {
        int n = min(64, end - base);
        int myidx = (lane < n) ? csr[base + lane] : 0;
        int j = 0;
        for (; j + 4 <= n; j += 4) {
            int s0 = __shfl(myidx, j);
            int s1 = __shfl(myidx, j + 1);
            int s2 = __shfl(myidx, j + 2);
            int s3 = __shfl(myidx, j + 3);
            float v0 = H[(size_t)s0 * 64 + lane];
            float v1 = H[(size_t)s1 * 64 + lane];
            float v2 = H[(size_t)s2 * 64 + lane];
            float v3 = H[(size_t)s3 * 64 + lane];
            acc += (v0 + v1) + (v2 + v3);
        }
        for (; j < n; ++j) {
            int s = __shfl(myidx, j);
            acc += H[(size_t)s * 64 + lane];
        }
    }
    float epsv = 1.0f + epsp[layer];
    U[(size_t)node * 64 + lane] = epsv * H[(size_t)node * 64 + lane] + acc;
}

// ===================== GEMMs ================================================
// V[r][c] = sum_k U[r][k] * W[k][c] + bias[c]
__global__ __launch_bounds__(256) void k_gemm_u(const float4* __restrict__ U,
        const float* __restrict__ W, const float* __restrict__ bias,
        float4* __restrict__ V, int M)
{
    __shared__ float4 Bs[64][16];   // W tile, 16 KB
    int tid = threadIdx.x;
    const float4* W4 = (const float4*)W;
#pragma unroll
    for (int i = 0; i < 4; ++i)
        ((float4*)Bs)[tid + 256 * i] = W4[tid + 256 * i];
    __syncthreads();

    int row = blockIdx.x * 256 + tid;
    if (row >= M) return;
    const float4* ur = U + (size_t)row * 16;

    float4 acc[16];
    const float4* b4 = (const float4*)bias;
#pragma unroll
    for (int c = 0; c < 16; ++c) acc[c] = b4[c];

#pragma unroll
    for (int kc = 0; kc < 4; ++kc) {
        float uv[16];
#pragma unroll
        for (int j = 0; j < 4; ++j) {
            float4 hv = ur[kc * 4 + j];
            uv[j * 4 + 0] = hv.x; uv[j * 4 + 1] = hv.y;
            uv[j * 4 + 2] = hv.z; uv[j * 4 + 3] = hv.w;
        }
#pragma unroll
        for (int k = 0; k < 16; ++k) {
            float a = uv[k];
            int kk = kc * 16 + k;
#pragma unroll
            for (int c = 0; c < 16; ++c) {
                float4 bv = Bs[kk][c];
                acc[c].x += a * bv.x;
                acc[c].y += a * bv.y;
                acc[c].z += a * bv.z;
                acc[c].w += a * bv.w;
            }
        }
    }
    float4* vr = V + (size_t)row * 16;
#pragma unroll
    for (int c = 0; c < 16; ++c) vr[c] = acc[c];
}

// Z[r][c] = sum_k relu(a[k]*Vin[r][k]+b[k]) * W[k][c] + bias[c]
__global__ __launch_bounds__(256) void k_gemm_bn(const float4* __restrict__ Vin,
        const float* __restrict__ S, const float* __restrict__ g,
        const float* __restrict__ bt, const float* __restrict__ W,
        const float* __restrict__ bias, float4* __restrict__ Z, int M)
{
    __shared__ float4 Bs[64][16];
    __shared__ float As_[64];
    __shared__ float Bb_[64];
    int tid = threadIdx.x;
    const float4* W4 = (const float4*)W;
#pragma unroll
    for (int i = 0; i < 4; ++i)
        ((float4*)Bs)[tid + 256 * i] = W4[tid + 256 * i];
    if (tid < 64) {
        float invM = 1.0f / (float)M;
        float mu = S[tid] * invM;
        float var = S[64 + tid] * invM - mu * mu;
        float a = g[tid] * rsqrtf(var + BN_EPS);
        As_[tid] = a;
        Bb_[tid] = bt[tid] - a * mu;
    }
    __syncthreads();

    int row = blockIdx.x * 256 + tid;
    if (row >= M) return;
    const float4* vr = Vin + (size_t)row * 16;

    float4 acc[16];
    const float4* b4 = (const float4*)bias;
#pragma unroll
    for (int c = 0; c < 16; ++c) acc[c] = b4[c];

#pragma unroll
    for (int kc = 0; kc < 4; ++kc) {
        float uv[16];
#pragma unroll
        for (int j = 0; j < 4; ++j) {
            float4 hv = vr[kc * 4 + j];
            int kb = kc * 16 + j * 4;
            uv[j * 4 + 0] = fmaxf(As_[kb + 0] * hv.x + Bb_[kb + 0], 0.0f);
            uv[j * 4 + 1] = fmaxf(As_[kb + 1] * hv.y + Bb_[kb + 1], 0.0f);
            uv[j * 4 + 2] = fmaxf(As_[kb + 2] * hv.z + Bb_[kb + 2], 0.0f);
            uv[j * 4 + 3] = fmaxf(As_[kb + 3] * hv.w + Bb_[kb + 3], 0.0f);
        }
#pragma unroll
        for (int k = 0; k < 16; ++k) {
            float a = uv[k];
            int kk = kc * 16 + k;
#pragma unroll
            for (int c = 0; c < 16; ++c) {
                float4 bv = Bs[kk][c];
                acc[c].x += a * bv.x;
                acc[c].y += a * bv.y;
                acc[c].z += a * bv.z;
                acc[c].w += a * bv.w;
            }
        }
    }
    float4* zr = Z + (size_t)row * 16;
#pragma unroll
    for (int c = 0; c < 16; ++c) zr[c] = acc[c];
}

// -------- column stats: S[0..63]=sum, S[64..127]=sumsq ----------------------
__global__ __launch_bounds__(256) void k_stats(const float4* __restrict__ V,
        float* __restrict__ S, int M)
{
    int tid = threadIdx.x;
    int q = tid & 15, rs = tid >> 4;
    float4 sum = make_float4(0.f, 0.f, 0.f, 0.f);
    float4 ss = make_float4(0.f, 0.f, 0.f, 0.f);
    for (int r = blockIdx.x * 16 + rs; r < M; r += gridDim.x * 16) {
        float4 v = V[(size_t)r * 16 + q];
        sum.x += v.x; sum.y += v.y; sum.z += v.z; sum.w += v.w;
        ss.x += v.x * v.x; ss.y += v.y * v.y; ss.z += v.z * v.z; ss.w += v.w * v.w;
    }
    sum.x += __shfl_xor(sum.x, 16); sum.y += __shfl_xor(sum.y, 16);
    sum.z += __shfl_xor(sum.z, 16); sum.w += __shfl_xor(sum.w, 16);
    ss.x += __shfl_xor(ss.x, 16);   ss.y += __shfl_xor(ss.y, 16);
    ss.z += __shfl_xor(ss.z, 16);   ss.w += __shfl_xor(ss.w, 16);
    sum.x += __shfl_xor(sum.x, 32); sum.y += __shfl_xor(sum.y, 32);
    sum.z += __shfl_xor(sum.z, 32); sum.w += __shfl_xor(sum.w, 32);
    ss.x += __shfl_xor(ss.x, 32);   ss.y += __shfl_xor(ss.y, 32);
    ss.z += __shfl_xor(ss.z, 32);   ss.w += __shfl_xor(ss.w, 32);

    __shared__ float4 LS[4][16];
    __shared__ float4 LQ[4][16];
    int wave = tid >> 6, lane = tid & 63;
    if (lane < 16) { LS[wave][lane] = sum; LQ[wave][lane] = ss; }
    __syncthreads();
    if (tid < 16) {
        float4 s0 = LS[0][tid], q0 = LQ[0][tid];
#pragma unroll
        for (int w = 1; w < 4; ++w) {
            float4 sw = LS[w][tid], qw = LQ[w][tid];
            s0.x += sw.x; s0.y += sw.y; s0.z += sw.z; s0.w += sw.w;
            q0.x += qw.x; q0.y += qw.y; q0.z += qw.z; q0.w += qw.w;
        }
        atomicAdd4(S + tid * 4, s0);
        atomicAdd4(S + 64 + tid * 4, q0);
    }
}

// -------- finalize: H = relu(a*Z+b) ----------------------------------------
__global__ __launch_bounds__(256) void k_finalize(const float4* __restrict__ Z,
        const float* __restrict__ S, const float* __restrict__ g,
        const float* __restrict__ bt, float4* __restrict__ H, int M, float invM)
{
    int q = threadIdx.x & 15;
    float a4[4], b4[4];
#pragma unroll
    for (int j = 0; j < 4; ++j) {
        int c = q * 4 + j;
        float mu = S[c] * invM;
        float var = S[64 + c] * invM - mu * mu;
        float a = g[c] * rsqrtf(var + BN_EPS);
        a4[j] = a;
        b4[j] = bt[c] - a * mu;
    }
    int total = M * 16;
    for (int u = blockIdx.x * 256 + threadIdx.x; u < total; u += gridDim.x * 256) {
        float4 z = Z[u];
        float4 h;
        h.x = fmaxf(a4[0] * z.x + b4[0], 0.f);
        h.y = fmaxf(a4[1] * z.y + b4[1], 0.f);
        h.z = fmaxf(a4[2] * z.z + b4[2], 0.f);
        h.w = fmaxf(a4[3] * z.w + b4[3], 0.f);
        H[u] = h;
    }
}

// -------- per-graph mean pool ----------------------------------------------
__global__ __launch_bounds__(256) void k_pool(const float4* __restrict__ H,
        const int* __restrict__ batch, float* __restrict__ POOL,
        float* __restrict__ CNT, int M, int chunk)
{
    int start = blockIdx.x * chunk;
    int end = min(M, start + chunk);
    int q = threadIdx.x & 15, rs = threadIdx.x >> 4;
    int curg = -1;
    float4 acc = make_float4(0.f, 0.f, 0.f, 0.f);
    float cl = 0.f;
    for (int r = start + rs; r < end; r += 16) {
        int gg = batch[r];
        float4 v = H[(size_t)r * 16 + q];
        if (gg != curg) {
            if (curg >= 0) {
                atomicAdd4(POOL + (size_t)curg * 64 + q * 4, acc);
                if (q == 0) unsafeAtomicAdd(CNT + curg, cl);
            }
            curg = gg;
            acc = make_float4(0.f, 0.f, 0.f, 0.f);
            cl = 0.f;
        }
        acc.x += v.x; acc.y += v.y; acc.z += v.z; acc.w += v.w;
        cl += 1.f;
    }
    if (curg >= 0) {
        atomicAdd4(POOL + (size_t)curg * 64 + q * 4, acc);
        if (q == 0) unsafeAtomicAdd(CNT + curg, cl);
    }
}

// -------- head --------------------------------------------------------------
__global__ __launch_bounds__(256) void k_head(const float* __restrict__ POOL,
        const float* __restrict__ CNT, const float* __restrict__ Wh,
        const float* __restrict__ bh, float* __restrict__ OUT, int ngraph)
{
    int lane = threadIdx.x & 63;
    int wv = threadIdx.x >> 6;
    int gidx = blockIdx.x * 4 + wv;
    if (gidx >= ngraph) return;
    float c = fmaxf(CNT[gidx], 1.0f);
    float v = POOL[(size_t)gidx * 64 + lane] / c * Wh[lane];
#pragma unroll
    for (int off = 1; off < 64; off <<= 1) v += __shfl_xor(v, off);
    if (lane == 0) OUT[gidx] = v + bh[0];
}

extern "C" void kernel_launch(void* const* d_in, const int* in_sizes, int n_in,
                              void* d_out, int out_size, void* d_ws, size_t ws_size,
                              hipStream_t stream)
{
    const float* x   = (const float*)d_in[0];
    const int*   ei  = (const int*)d_in[1];
    const int*   bat = (const int*)d_in[2];
    const float* W1  = (const float*)d_in[3];
    const float* b1  = (const float*)d_in[4];
    const float* g1  = (const float*)d_in[5];
    const float* bt1 = (const float*)d_in[6];
    const float* W2  = (const float*)d_in[7];
    const float* b2  = (const float*)d_in[8];
    const float* g2  = (const float*)d_in[9];
    const float* bt2 = (const float*)d_in[10];
    const float* eps = (const float*)d_in[11];
    const float* Wh  = (const float*)d_in[12];
    const float* bh  = (const float*)d_in[13];
    float* out = (float*)d_out;

    int M = in_sizes[0] / 64;
    int nedges = in_sizes[1] / 2;
    const int* src = ei;
    const int* dst = ei + nedges;
    const int NG = 512;

    float* ws = (float*)d_ws;
    size_t NE = (size_t)M * 64;
    float* h    = ws;
    float* u    = ws + NE;          // aliased with z (u dead before z written)
    float* v    = ws + 2 * NE;
    float* z    = u;
    float* S1   = ws + 3 * NE;      // 4 layers x 128
    float* S2   = S1 + 512;
    float* POOL = S2 + 512;         // 512 x 64
    float* CNT  = POOL + (size_t)NG * 64;  // 512

    int* rowptr = (int*)(CNT + NG);        // M+1
    int* fillp  = rowptr + (M + 1);        // M
    int* deg    = fillp + M;               // M
    int* incl   = deg + M;                 // M
    int* bsum   = incl + M;                // 512
    int* csr    = bsum + 512;              // nedges

    hipMemsetAsync(deg, 0, (size_t)M * sizeof(int), stream);
    hipMemsetAsync(S1, 0, (512 + 512 + (size_t)NG * 64 + NG) * sizeof(float), stream);

    int edgeGrid = (nedges + 255) / 256;
    int nodeGrid = (M + 255) / 256;

    // ---- CSR build ----
    k_count<<<edgeGrid, 256, 0, stream>>>(dst, deg, nedges);
    int NB = (M + 255) / 256;
    k_scanA<<<NB, 256, 0, stream>>>(deg, incl, bsum, M);
    k_scanB<<<1, 512, 0, stream>>>(bsum, NB);
    k_scanC<<<NB, 256, 0, stream>>>(deg, incl, bsum, rowptr, fillp, M);
    k_fill<<<edgeGrid, 256, 0, stream>>>(src, dst, fillp, csr, nedges);

    int gemmGrid = (M + 255) / 256;
    int gatherGrid = (M + 3) / 4;

    for (int i = 0; i < 4; ++i) {
        const float* hin = (i == 0) ? x : h;
        k_gather<<<gatherGrid, 256, 0, stream>>>(hin, rowptr, csr, eps, i, u, M);
        k_gemm_u<<<gemmGrid, 256, 0, stream>>>((const float4*)u,
                W1 + (size_t)i * 4096, b1 + i * 64, (float4*)v, M);
        k_stats<<<400, 256, 0, stream>>>((const float4*)v, S1 + i * 128, M);
        k_gemm_bn<<<gemmGrid, 256, 0, stream>>>((const float4*)v, S1 + i * 128,
                g1 + i * 64, bt1 + i * 64, W2 + (size_t)i * 4096, b2 + i * 64,
                (float4*)z, M);
        k_stats<<<400, 256, 0, stream>>>((const float4*)z, S2 + i * 128, M);
        k_finalize<<<2048, 256, 0, stream>>>((const float4*)z, S2 + i * 128,
                g2 + i * 64, bt2 + i * 64, (float4*)h, M, 1.0f / M);
    }
    int chunk = (M + 511) / 512;
    k_pool<<<512, 256, 0, stream>>>((const float4*)h, bat, POOL, CNT, M, chunk);
    k_head<<<(NG + 3) / 4, 256, 0, stream>>>(POOL, CNT, Wh, bh, out, NG);
}